// Round 8
// baseline (315.415 us; speedup 1.0000x reference)
//
#include <hip/hip_runtime.h>
#include <stdint.h>

#define Bn 2
#define Sn 2048
#define Dn 1024
#define Hn 16
#define DKn 64
#define EDn 256

typedef __attribute__((ext_vector_type(8))) short bvec8;   // 8 bf16 (4 VGPR)
typedef __attribute__((ext_vector_type(4))) float fvec4;   // 4 fp32 acc

#define MFMA(a, b, c) __builtin_amdgcn_mfma_f32_16x16x32_bf16(a, b, c, 0, 0, 0)

__device__ __forceinline__ float b2f(unsigned short u) {
  return __uint_as_float(((unsigned)u) << 16);
}
__device__ __forceinline__ unsigned short f2b(float x) {
  unsigned u = __float_as_uint(x);
  u += 0x7fffu + ((u >> 16) & 1u);
  return (unsigned short)(u >> 16);
}
// pack two fp32 -> two bf16 (round-nearest, ties-away; ties have prob ~0)
__device__ __forceinline__ unsigned pk2(float a, float b) {
  return ((__float_as_uint(a) + 0x8000u) >> 16) |
         ((__float_as_uint(b) + 0x8000u) & 0xffff0000u);
}
// async global->LDS, 16B/lane; LDS dest is wave-uniform base + lane*16
__device__ __forceinline__ void g2l(const unsigned short* g, unsigned short* l) {
  __builtin_amdgcn_global_load_lds(
      (const __attribute__((address_space(1))) void*)g,
      (__attribute__((address_space(3))) void*)l, 16, 0, 0);
}

// ---------------- prep1: trW + trE + xb + alphas + trVT (all independent) --
// blocks: [0,1024) trW | [1024,1028) trE | [1028,5124) xb | [5124,5156) alphas
//         | [5156,5220) trVT
__global__ __launch_bounds__(256) void k_prep1(
    const float* __restrict__ x, const float* __restrict__ w0,
    const float* __restrict__ w1, const float* __restrict__ w2,
    const float* __restrict__ w3, const float* __restrict__ traces,
    const float* __restrict__ vtr, const float* __restrict__ Wexp,
    unsigned short* __restrict__ Wt, unsigned short* __restrict__ WexpT,
    unsigned short* __restrict__ xb, float* __restrict__ alphas,
    unsigned short* __restrict__ VTt) {
  const int blk = blockIdx.x;
  const int tid = threadIdx.x;
  __shared__ unsigned short Tl[64][72];
  if (blk < 1024) {  // trW: Wt[z][n][k] = W_z[k][n] bf16
    int z = blk >> 8, t = blk & 255;
    int n0 = (t & 15) * 64, k0 = (t >> 4) * 64;
    const float* src = (z == 0) ? w0 : ((z == 1) ? w1 : ((z == 2) ? w2 : w3));
    unsigned short* d = Wt + (size_t)z * Dn * Dn;
#pragma unroll
    for (int i = 0; i < 4; ++i) {
      int q = tid + 256 * i;
      int kr = q >> 4, c4 = q & 15;
      float4 v = *(const float4*)&src[(size_t)(k0 + kr) * Dn + n0 + 4 * c4];
      ushort4 u;
      u.x = f2b(v.x); u.y = f2b(v.y); u.z = f2b(v.z); u.w = f2b(v.w);
      *(ushort4*)&Tl[kr][4 * c4] = u;
    }
    __syncthreads();
#pragma unroll
    for (int i = 0; i < 4; ++i) {
      int q = tid + 256 * i;
      int nr = q >> 4, c4 = q & 15;
      ushort4 u;
      u.x = Tl[4 * c4 + 0][nr]; u.y = Tl[4 * c4 + 1][nr];
      u.z = Tl[4 * c4 + 2][nr]; u.w = Tl[4 * c4 + 3][nr];
      *(ushort4*)&d[(size_t)(n0 + nr) * Dn + k0 + 4 * c4] = u;
    }
  } else if (blk < 1028) {  // trE: WexpT[e][d]
    int e0 = (blk - 1024) * 64;
#pragma unroll
    for (int i = 0; i < 4; ++i) {
      int q = tid + 256 * i;
      int dr = q >> 4, c4 = q & 15;
      float4 v = *(const float4*)&Wexp[(size_t)dr * EDn + e0 + 4 * c4];
      ushort4 u;
      u.x = f2b(v.x); u.y = f2b(v.y); u.z = f2b(v.z); u.w = f2b(v.w);
      *(ushort4*)&Tl[dr][4 * c4] = u;
    }
    __syncthreads();
#pragma unroll
    for (int i = 0; i < 4; ++i) {
      int q = tid + 256 * i;
      int er = q >> 4, c4 = q & 15;
      ushort4 u;
      u.x = Tl[4 * c4 + 0][er]; u.y = Tl[4 * c4 + 1][er];
      u.z = Tl[4 * c4 + 2][er]; u.w = Tl[4 * c4 + 3][er];
      *(ushort4*)&WexpT[(size_t)(e0 + er) * DKn + 4 * c4] = u;
    }
  } else if (blk < 5124) {  // xb: x fp32 -> bf16
    size_t i = ((size_t)(blk - 1028) * 256 + tid) * 4;
    float4 v = *(const float4*)&x[i];
    ushort4 u;
    u.x = f2b(v.x); u.y = f2b(v.y); u.z = f2b(v.z); u.w = f2b(v.w);
    *(ushort4*)&xb[i] = u;
  } else if (blk < 5156) {  // alphas
    int a = blk - 5124;
    const float* base;
    int n;
    if (a < 16) { base = traces + a * DKn * DKn; n = DKn * DKn; }
    else        { base = vtr + (a - 16) * EDn * DKn; n = EDn * DKn; }
    float s = 0.f;
    for (int i = tid; i < n; i += 256) { float v = base[i]; s += v * v; }
    __shared__ float red[256];
    red[tid] = s;
    __syncthreads();
    for (int off = 128; off > 0; off >>= 1) {
      if (tid < off) red[tid] += red[tid + off];
      __syncthreads();
    }
    if (tid == 0) alphas[a] = 0.05f / (1.f + sqrtf(red[0]));
  } else {  // trVT: VTt[h][d][e]
    int t = blk - 5156;
    int e0 = (t & 3) * 64, h = t >> 2;
    const float* src = vtr + (size_t)h * EDn * DKn;
    unsigned short* dst = VTt + (size_t)h * DKn * EDn;
#pragma unroll
    for (int i = 0; i < 4; ++i) {
      int q = tid + 256 * i;
      int er = q >> 4, c4 = q & 15;
      float4 v = *(const float4*)&src[(size_t)(e0 + er) * DKn + 4 * c4];
      ushort4 u;
      u.x = f2b(v.x); u.y = f2b(v.y); u.z = f2b(v.z); u.w = f2b(v.w);
      *(ushort4*)&Tl[er][4 * c4] = u;
    }
    __syncthreads();
#pragma unroll
    for (int i = 0; i < 4; ++i) {
      int q = tid + 256 * i;
      int dr = q >> 4, c4 = q & 15;
      ushort4 u;
      u.x = Tl[4 * c4 + 0][dr]; u.y = Tl[4 * c4 + 1][dr];
      u.z = Tl[4 * c4 + 2][dr]; u.w = Tl[4 * c4 + 3][dr];
      *(ushort4*)&dst[(size_t)dr * EDn + e0 + 4 * c4] = u;
    }
  }
}

// ---------------- prep2: Mt[h][e][k] = SC*(I + alpha_h*T_h)[k][e] ----------
// SC = 0.125*log2(e): folds both 1/sqrt(dk) and the exp2 base change into Q'.
__global__ __launch_bounds__(256) void k_mkM(const float* __restrict__ tr,
                                             const float* __restrict__ alph,
                                             unsigned short* __restrict__ Mt) {
  const float SC = 0.125f * 1.4426950408889634f;
  int h = blockIdx.x;
  float a = alph[h] * SC;
  const float* th = tr + (size_t)h * DKn * DKn;
  unsigned short* mh = Mt + (size_t)h * DKn * DKn;
  for (int i = threadIdx.x; i < DKn * DKn; i += 256) {
    int e = i >> 6, k = i & 63;
    float v = a * th[(size_t)k * DKn + e] + ((e == k) ? SC : 0.f);
    mh[i] = f2b(v);
  }
}

// ---------------- MFMA GEMM: 128x128, BK=32, async LDS staging -------------
// MODE 0: A bf16; z=0,1 -> Qb/Kb (b,h,s,dk) via swapped-operand MFMA (packed
//         ushort4 stores); z=2 -> Vt (bh,dk,s) via normal order.
// MODE 1: A bf16 (ATb), C fp32 d_out via swapped order (packed float4).
template <int MODE>
__global__ __launch_bounds__(256) void k_gemm(
    const unsigned short* __restrict__ Ab,
    const unsigned short* __restrict__ BtBase, unsigned short* __restrict__ Qb,
    unsigned short* __restrict__ Kb, unsigned short* __restrict__ VtOut,
    float* __restrict__ Cout) {
  const int z = (MODE == 0) ? blockIdx.z : 0;
  const unsigned short* Bt = BtBase + (size_t)z * Dn * Dn;
  __shared__ unsigned short As[128 * 32];
  __shared__ unsigned short Bs[128 * 32];
  const int tid = threadIdx.x;
  const int w = tid >> 6, lane = tid & 63, qd = lane >> 4, cc = lane & 15;
  const int m0 = blockIdx.y * 128, n0 = blockIdx.x * 128;
  const int mW = 64 * (w >> 1), nW = 64 * (w & 1);
  const int srow = lane >> 2;                       // 0..15
  const int schk = 8 * ((lane & 3) ^ (srow & 3));   // swizzled source chunk
  const int r0 = 32 * w + srow, r1 = r0 + 16;
  const bool swap = (MODE == 1) || (z != 2);
  fvec4 acc[4][4];
#pragma unroll
  for (int i = 0; i < 4; ++i)
#pragma unroll
    for (int j = 0; j < 4; ++j) acc[i][j] = (fvec4){0.f, 0.f, 0.f, 0.f};

  for (int k0 = 0; k0 < Dn; k0 += 32) {
    g2l(&Ab[(size_t)(m0 + r0) * Dn + k0 + schk], &As[1024 * w]);
    g2l(&Ab[(size_t)(m0 + r1) * Dn + k0 + schk], &As[1024 * w + 512]);
    g2l(&Bt[(size_t)(n0 + r0) * Dn + k0 + schk], &Bs[1024 * w]);
    g2l(&Bt[(size_t)(n0 + r1) * Dn + k0 + schk], &Bs[1024 * w + 512]);
    __syncthreads();
    bvec8 af[4], bf[4];
#pragma unroll
    for (int i = 0; i < 4; ++i) {
      int ra = mW + 16 * i + cc;
      af[i] = *(const bvec8*)&As[ra * 32 + 8 * (qd ^ (ra & 3))];
      int rb = nW + 16 * i + cc;
      bf[i] = *(const bvec8*)&Bs[rb * 32 + 8 * (qd ^ (rb & 3))];
    }
    if (swap) {
#pragma unroll
      for (int i = 0; i < 4; ++i)
#pragma unroll
        for (int j = 0; j < 4; ++j) acc[i][j] = MFMA(bf[j], af[i], acc[i][j]);
    } else {
#pragma unroll
      for (int i = 0; i < 4; ++i)
#pragma unroll
        for (int j = 0; j < 4; ++j) acc[i][j] = MFMA(af[i], bf[j], acc[i][j]);
    }
    __syncthreads();
  }
#pragma unroll
  for (int i = 0; i < 4; ++i)
#pragma unroll
    for (int j = 0; j < 4; ++j) {
      if (MODE == 1) {
        // swapped: rows(M)=n (d, 4 consecutive), cols(N)=m (s)
        int s = m0 + mW + 16 * i + cc;
        int nb = n0 + nW + 16 * j + 4 * qd;
        float4 v = make_float4(acc[i][j][0], acc[i][j][1], acc[i][j][2],
                               acc[i][j][3]);
        *(float4*)&Cout[(size_t)s * Dn + nb] = v;
      } else if (z == 2) {
        // normal: rows(M)=m (s, 4 consecutive), cols(N)=n (h,dk)
        int rowb = m0 + mW + 16 * i + 4 * qd;
        int col = n0 + nW + 16 * j + cc;
        int b = rowb >> 11, s = rowb & 2047;
        int h = col >> 6, dk = col & 63;
        ushort4 u;
        u.x = f2b(acc[i][j][0]); u.y = f2b(acc[i][j][1]);
        u.z = f2b(acc[i][j][2]); u.w = f2b(acc[i][j][3]);
        *(ushort4*)&VtOut[(((size_t)(b * Hn + h)) * DKn + dk) * Sn + s] = u;
      } else {
        // swapped: rows(M)=n (h,dk; 4 consecutive dk), cols(N)=m (s)
        int s = m0 + mW + 16 * i + cc;
        int col = n0 + nW + 16 * j + 4 * qd;
        int b = s >> 11;
        int sm = s & 2047;
        int h = col >> 6, dk = col & 63;
        unsigned short* Cb = (z == 0) ? Qb : Kb;
        ushort4 u;
        u.x = f2b(acc[i][j][0]); u.y = f2b(acc[i][j][1]);
        u.z = f2b(acc[i][j][2]); u.w = f2b(acc[i][j][3]);
        *(ushort4*)&Cb[(((size_t)(b * Hn + h)) * Sn + sm) * DKn + dk] = u;
      }
    }
}

// ---------------- pattern separation: LDS-resident tables, swizzled --------
__global__ __launch_bounds__(256, 2) void k_pattsep(
    const unsigned short* __restrict__ Qb,
    const unsigned short* __restrict__ WexpT,  // [256][64] bf16
    const unsigned short* __restrict__ VTt,    // [16][64][256] bf16
    const float* __restrict__ alphas, unsigned short* __restrict__ ATb) {
  __shared__ uint4 Wl4[2048];
  __shared__ uint4 Vl4[2048];
  __shared__ uint4 Ps4[4][256];
  const int tile = blockIdx.x, bh = blockIdx.y;
  const int b = bh >> 4, h = bh & 15;
  const int tid = threadIdx.x;
  const int w = tid >> 6, lane = tid & 63, qd = lane >> 4, cc = lane & 15;
  const float avt = alphas[16 + h];

  const uint4* wsrc = (const uint4*)WexpT;
  const uint4* vsrc = (const uint4*)(VTt + (size_t)h * DKn * EDn);
  for (int i = tid; i < 2048; i += 256) {
    int e = i >> 3, c = i & 7;
    Wl4[e * 8 + (c ^ (e & 7))] = wsrc[i];
    int d = i >> 5, c2 = i & 31;
    Vl4[d * 32 + (c2 ^ (d & 7))] = vsrc[i];
  }
  __syncthreads();

  const unsigned short* Wls = (const unsigned short*)Wl4;
  const unsigned short* Vls = (const unsigned short*)Vl4;
  unsigned short* Pw = (unsigned short*)Ps4[w];

  for (int rg = 0; rg < 2; ++rg) {
    const int s0 = tile * 128 + w * 32 + rg * 16;
    bvec8 aq0 = {}, aq1 = {};
    const int srow = s0 + cc;
    if (srow > 0) {
      const unsigned short* qp = Qb + ((size_t)bh * Sn + srow - 1) * DKn;
      aq0 = *(const bvec8*)&qp[8 * qd];
      aq1 = *(const bvec8*)&qp[32 + 8 * qd];
    }
    fvec4 E[16];
#pragma unroll
    for (int j = 0; j < 16; ++j) {
      const int e = 16 * j + cc;
      const unsigned short* wr = Wls + e * 64;
      bvec8 b0 = *(const bvec8*)&wr[8 * (qd ^ (e & 7))];
      bvec8 b1 = *(const bvec8*)&wr[8 * ((4 + qd) ^ (e & 7))];
      fvec4 zv = {0.f, 0.f, 0.f, 0.f};
      zv = MFMA(aq0, b0, zv);
      E[j] = MFMA(aq1, b1, zv);
    }
#pragma unroll
    for (int j = 0; j < 16; ++j)
#pragma unroll
      for (int r = 0; r < 4; ++r) E[j][r] = fmaxf(E[j][r], 0.f);

    float thr[4];
#pragma unroll
    for (int r = 0; r < 4; ++r) {
      unsigned cur = 0u;
      bool done = false;
      for (int bit = 30; bit >= 0; --bit) {
        unsigned cand = cur | (1u << bit);
        float t = __uint_as_float(cand);
        int cnt = 0;
#pragma unroll
        for (int j = 0; j < 16; ++j) cnt += (E[j][r] >= t) ? 1 : 0;
        cnt += __shfl_xor(cnt, 1);
        cnt += __shfl_xor(cnt, 2);
        cnt += __shfl_xor(cnt, 4);
        cnt += __shfl_xor(cnt, 8);
        if (!done && cnt >= 32) {
          cur = cand;
          if (cnt == 32) done = true;
        }
        if (__all(done)) break;
      }
      thr[r] = __uint_as_float(cur);
    }

    fvec4 acc2[4];
#pragma unroll
    for (int j2 = 0; j2 < 4; ++j2) acc2[j2] = (fvec4){0.f, 0.f, 0.f, 0.f};

#pragma unroll
    for (int half = 0; half < 2; ++half) {
#pragma unroll
      for (int j = 0; j < 8; ++j) {
        const int jj = j + 8 * half;
#pragma unroll
        for (int r = 0; r < 4; ++r) {
          float v = E[jj][r];
          bool sel = (v >= thr[r]) && (v > 0.f);
          int row = 4 * qd + r;
          int s = 16 * j + cc;
          int ch = (s >> 3) ^ (row & 7);
          Pw[row * 128 + ch * 8 + (s & 7)] = sel ? f2b(v) : (unsigned short)0;
        }
      }
#pragma unroll
      for (int j2 = 0; j2 < 4; ++j2) {
        const int d = 16 * j2 + cc;
        const unsigned short* vr = Vls + d * 256;
#pragma unroll
        for (int c = 0; c < 4; ++c) {
          int cg = 4 * (c + 4 * half) + qd;
          bvec8 bv = *(const bvec8*)&vr[8 * (cg ^ (d & 7))];
          int ca = 4 * c + qd;
          bvec8 ap = *(const bvec8*)&Pw[cc * 128 + 8 * (ca ^ (cc & 7))];
          acc2[j2] = MFMA(ap, bv, acc2[j2]);
        }
      }
    }
#pragma unroll
    for (int j2 = 0; j2 < 4; ++j2)
#pragma unroll
      for (int r = 0; r < 4; ++r) {
        int row = s0 + 4 * qd + r;
        ATb[((size_t)(b * Sn + row)) * Dn + h * DKn + 16 * j2 + cc] =
            f2b(avt * acc2[j2][r]);
      }
  }
}

// ---------------- flash attention + fused fold, S^T raw-exp softmax --------
// Scores come out pre-scaled by log2e (folded in Mt): p = exp2(s) directly;
// the implicit constant offset cancels in O/l.
__global__ __launch_bounds__(256) void k_attn(
    const unsigned short* __restrict__ Qb, const unsigned short* __restrict__ Kb,
    const unsigned short* __restrict__ Vt, const unsigned short* __restrict__ Mt,
    unsigned short* __restrict__ ATb) {
  __shared__ unsigned short Kd[64 * 64];  // unpadded, chunk-swizzled c^(r&7)
  __shared__ unsigned short Vl[64 * 64];
  __shared__ unsigned short Ps[4][16][72];  // per-wave P, row-major [q][k]
  const int bh = blockIdx.x, qt = blockIdx.y;
  const int b = bh >> 4, h = bh & 15;
  const int tid = threadIdx.x;
  const int w = tid >> 6, lane = tid & 63, qd = lane >> 4, cc = lane & 15;

  // fused fold: Q' = Qraw @ M  (Kd reused as per-wave Qd before first barrier)
  const unsigned short* qg = Qb + ((size_t)bh * Sn + qt * 64 + w * 16) * DKn;
  bvec8 a0 = *(const bvec8*)&qg[cc * DKn + 8 * qd];
  bvec8 a1 = *(const bvec8*)&qg[cc * DKn + 32 + 8 * qd];
  const unsigned short* mh = Mt + (size_t)h * DKn * DKn;
#pragma unroll
  for (int j = 0; j < 4; ++j) {
    bvec8 b0 = *(const bvec8*)&mh[(size_t)(16 * j + cc) * DKn + 8 * qd];
    bvec8 b1 = *(const bvec8*)&mh[(size_t)(16 * j + cc) * DKn + 32 + 8 * qd];
    fvec4 zz = {0.f, 0.f, 0.f, 0.f};
    zz = MFMA(a0, b0, zz);
    zz = MFMA(a1, b1, zz);
#pragma unroll
    for (int r = 0; r < 4; ++r) {
      int qr = 4 * qd + r;
      Kd[(16 * w + qr) * 64 + 8 * ((2 * j + (cc >> 3)) ^ (qr & 7)) + (cc & 7)] =
          f2b(zz[r]);
    }
  }
  bvec8 aq0 = *(const bvec8*)&Kd[(16 * w + cc) * 64 + 8 * (qd ^ (cc & 7))];
  bvec8 aq1 =
      *(const bvec8*)&Kd[(16 * w + cc) * 64 + 8 * ((qd + 4) ^ (cc & 7))];

  float l_s = 0.f;  // softmax denominator for q = cc (this lane's column)
  fvec4 O[4];
#pragma unroll
  for (int j = 0; j < 4; ++j) O[j] = (fvec4){0.f, 0.f, 0.f, 0.f};

  const int vrow = lane >> 3;                       // 0..7
  const int vchk = 8 * ((lane & 7) ^ (vrow & 7));   // swizzled source chunk
  const unsigned short* kgb = Kb + (size_t)bh * Sn * DKn;
  const unsigned short* vgb = Vt + (size_t)bh * DKn * Sn;

  for (int kt = 0; kt < Sn / 64; ++kt) {
    __syncthreads();
    const unsigned short* kg = kgb + (size_t)kt * 64 * DKn;
    g2l(&kg[(size_t)(16 * w + vrow) * 64 + vchk], &Kd[1024 * w]);
    g2l(&kg[(size_t)(16 * w + 8 + vrow) * 64 + vchk], &Kd[1024 * w + 512]);
    g2l(&vgb[(size_t)(16 * w + vrow) * Sn + kt * 64 + vchk], &Vl[1024 * w]);
    g2l(&vgb[(size_t)(16 * w + 8 + vrow) * Sn + kt * 64 + vchk],
        &Vl[1024 * w + 512]);
    __syncthreads();
    // S^T: sc[j] rows = k-cols 16j+4qd+r, col = q = cc
    fvec4 sc[4];
#pragma unroll
    for (int j = 0; j < 4; ++j) {
      int rk = 16 * j + cc;
      bvec8 b0 = *(const bvec8*)&Kd[rk * 64 + 8 * (qd ^ (cc & 7))];
      bvec8 b1 = *(const bvec8*)&Kd[rk * 64 + 8 * ((qd + 4) ^ (cc & 7))];
      fvec4 zz = {0.f, 0.f, 0.f, 0.f};
      zz = MFMA(b0, aq0, zz);
      sc[j] = MFMA(b1, aq1, zz);
    }
#pragma unroll
    for (int j = 0; j < 4; ++j) {
      float p0 = __builtin_amdgcn_exp2f(sc[j][0]);
      float p1 = __builtin_amdgcn_exp2f(sc[j][1]);
      float p2 = __builtin_amdgcn_exp2f(sc[j][2]);
      float p3 = __builtin_amdgcn_exp2f(sc[j][3]);
      l_s += (p0 + p1) + (p2 + p3);
      uint2 u;
      u.x = pk2(p0, p1);
      u.y = pk2(p2, p3);
      *(uint2*)&Ps[w][cc][16 * j + 4 * qd] = u;
    }
    bvec8 ap0 = *(const bvec8*)&Ps[w][cc][8 * qd];
    bvec8 ap1 = *(const bvec8*)&Ps[w][cc][32 + 8 * qd];
#pragma unroll
    for (int j = 0; j < 4; ++j) {
      int rv = 16 * j + cc;
      bvec8 v0 = *(const bvec8*)&Vl[rv * 64 + 8 * (qd ^ (cc & 7))];
      bvec8 v1 = *(const bvec8*)&Vl[rv * 64 + 8 * ((qd + 4) ^ (cc & 7))];
      O[j] = MFMA(ap0, v0, O[j]);
      O[j] = MFMA(ap1, v1, O[j]);
    }
  }
  // complete l for q=cc (sum the 4 quad partials), then fetch per-row inv
  l_s += __shfl_xor(l_s, 16);
  l_s += __shfl_xor(l_s, 32);
  float linv = 1.f / l_s;
  float inv[4];
#pragma unroll
  for (int r = 0; r < 4; ++r) inv[r] = __shfl(linv, 4 * qd + r);
#pragma unroll
  for (int j = 0; j < 4; ++j)
#pragma unroll
    for (int r = 0; r < 4; ++r) {
      int row = qt * 64 + w * 16 + 4 * qd + r;
      unsigned short* p =
          ATb + ((size_t)(b * Sn + row)) * Dn + h * DKn + 16 * j + cc;
      *p = f2b(b2f(*p) + O[j][r] * inv[r]);
    }
}

// ---------------- launch ----------------
extern "C" void kernel_launch(void* const* d_in, const int* in_sizes, int n_in,
                              void* d_out, int out_size, void* d_ws,
                              size_t ws_size, hipStream_t stream) {
  const float* x = (const float*)d_in[0];
  const float* Wq = (const float*)d_in[1];
  const float* Wk = (const float*)d_in[2];
  const float* Wv = (const float*)d_in[3];
  const float* Wo = (const float*)d_in[4];
  const float* traces = (const float*)d_in[5];
  const float* vtr = (const float*)d_in[6];
  const float* Wexp = (const float*)d_in[7];

  const size_t NQ = (size_t)Bn * Hn * Sn * DKn;  // 4,194,304
  unsigned short* Qb = (unsigned short*)d_ws;
  unsigned short* Kb = Qb + NQ;
  unsigned short* Vt = Kb + NQ;                // (bh, dk, s) bf16
  unsigned short* Wt = Vt + NQ;                // 4 x D*D bf16 = NQ shorts
  unsigned short* Mt = Wt + NQ;                // 16*64*64 = 65536
  unsigned short* WexpT = Mt + 65536;          // 256*64 = 16384
  unsigned short* VTt = WexpT + 16384;         // 16*64*256 = 262144
  float* alph = (float*)(VTt + 262144);        // 32 floats
  unsigned short* ATb = (unsigned short*)(alph + 32);  // (B,S,D) bf16, 8MB
  unsigned short* xb = ATb;                    // aliased: xb dead before pattsep

  k_prep1<<<5220, 256, 0, stream>>>(x, Wq, Wk, Wv, Wo, traces, vtr, Wexp, Wt,
                                    WexpT, xb, alph, VTt);
  k_mkM<<<16, 256, 0, stream>>>(traces, alph, Mt);
  k_gemm<0><<<dim3(8, 32, 3), 256, 0, stream>>>(xb, Wt, Qb, Kb, Vt, nullptr);
  k_pattsep<<<dim3(16, 32), 256, 0, stream>>>(Qb, WexpT, VTt, alph, ATb);
  k_attn<<<dim3(32, 32), 256, 0, stream>>>(Qb, Kb, Vt, Mt, ATb);
  k_gemm<1><<<dim3(8, 32, 1), 256, 0, stream>>>(
      ATb, Wt + 3 * (size_t)Dn * Dn, nullptr, nullptr, nullptr,
      (float*)d_out);
}